// Round 2
// baseline (114.557 us; speedup 1.0000x reference)
//
#include <hip/hip_runtime.h>

#define HH   128
#define WW   128
#define HW   (HH * WW)
#define CC   64
#define TILE 16
#define HALO 20
#define NHP  (HALO * HALO)   // 400 halo pixels = 25 exact 16-px MFMA tiles
#define SWZ(r) (((r) >> 1) & 7)

typedef unsigned int uint32;
typedef _Float16 h2   __attribute__((ext_vector_type(2)));
typedef __fp16   h2b  __attribute__((ext_vector_type(2)));
typedef _Float16 h8   __attribute__((ext_vector_type(8)));
typedef float    f32x4 __attribute__((ext_vector_type(4)));

__device__ __forceinline__ uint32 pkrtz(float a, float b) {
    h2b r = __builtin_amdgcn_cvt_pkrtz(a, b);
    return __builtin_bit_cast(uint32, r);
}
__device__ __forceinline__ float dot2(uint32 a, uint32 b, float c) {
#if __has_builtin(__builtin_amdgcn_fdot2)
    return __builtin_amdgcn_fdot2(__builtin_bit_cast(h2b, a),
                                  __builtin_bit_cast(h2b, b), c, false);
#else
    h2 x = __builtin_bit_cast(h2, a), y = __builtin_bit_cast(h2, b);
    return c + (float)x.x * (float)y.x + (float)x.y * (float)y.y;
#endif
}
__device__ __forceinline__ f32x4 mfma16(uint4 a, uint4 b, f32x4 c) {
    return __builtin_amdgcn_mfma_f32_16x16x32_f16(
        __builtin_bit_cast(h8, a), __builtin_bit_cast(h8, b), c, 0, 0, 0);
}
__device__ __forceinline__ uint4 pack_w8(const float* __restrict__ w) {
    const float4 lo = *(const float4*)w;
    const float4 hi = *(const float4*)(w + 4);
    uint4 r;
    r.x = pkrtz(lo.x, lo.y); r.y = pkrtz(lo.z, lo.w);
    r.z = pkrtz(hi.x, hi.y); r.w = pkrtz(hi.z, hi.w);
    return r;
}

// ---------------------------------------------------------------------------
// Fused local attention, 16x16 tiles, 1 block/CU, 16 waves, 5 barriers.
// Software-pipelined (T14): all global loads issued at kernel start; x-halo
// is packed/written to LDS only AFTER q-conv (HBM latency hides under MFMA).
// Phase overlap: q-write || v-conv (A-write vs B-read), v-write || scores
// (B-write vs A-read), agg-read(B) || agg-write(A).
//   P0: issue y,x loads; y->A.            barrier[1]
//   P1: q-conv(A); x->B.                  barrier[2]
//   P2: q->A; v-conv(B); xres from B.     barrier[3]
//   P3: v->B; scores(A); softmax.         barrier[4]
//   P4: agg(B); agg->A.                   barrier[5]
//   P5: final conv(A) + residual + store.
// ---------------------------------------------------------------------------
__global__ __launch_bounds__(1024, 4)
void fused_attn(const float* __restrict__ x, const float* __restrict__ y,
                const float* __restrict__ wx, const float* __restrict__ bx,
                const float* __restrict__ wy, const float* __restrict__ by,
                const float* __restrict__ wo, const float* __restrict__ bo,
                float* __restrict__ out)
{
    __shared__ uint32 Ah[NHP * 32];   // 50 KiB
    __shared__ uint32 Bh[NHP * 32];   // 50 KiB

    // ---- XCD-aware tile mapping: lin%8 = XCD; each XCD owns a contiguous
    // 4-tile-row x 8-tile-col half-batch region (halo overlap stays in-L2) ----
    const int lin  = blockIdx.x;          // 0..255
    const int xcd  = lin & 7;
    const int rr   = lin >> 3;            // 0..31 within XCD
    const int b    = xcd >> 1;            // 2 XCDs per batch
    const int half = xcd & 1;             // top/bottom 4 tile-rows
    const int ty0  = ((rr >> 3) + half * 4) * TILE;
    const int tx0  = (rr & 7) * TILE;

    const int t = threadIdx.x;

    // ---- P0: issue ALL halo loads (y and x); pack y -> A; keep x in regs ----
    float2 yv0[8], xv0[8], yv1[8], xv1[8];
    int pix0 = 0, co0 = 0, pix1 = 0, co1 = 0;
    const bool has1 = t < (NHP * 8 / 2 - 1024);        // 1600 pair-items
    {
        const int i = t;
        co0 = i / 200;
        const int rem = i - co0 * 200;
        const int hy = rem / 10, hx = (rem - hy * 10) * 2;
        pix0 = hy * HALO + hx;
        int gy = ty0 + hy - 2, gx = tx0 + hx - 2;      // gx even
        const bool ok = ((unsigned)gy < HH) & ((unsigned)gx < (WW - 1));
        if (!ok) { gy = 0; gx = 0; }     // clamp; conv out zeroed at write
        const size_t base = (size_t)b * CC * HW + (size_t)(co0 * 8) * HW
                          + (size_t)gy * WW + gx;
        #pragma unroll
        for (int j = 0; j < 8; ++j) {
            yv0[j] = *(const float2*)(y + base + (size_t)j * HW);
            xv0[j] = *(const float2*)(x + base + (size_t)j * HW);
        }
    }
    if (has1) {
        const int i = t + 1024;
        co1 = i / 200;
        const int rem = i - co1 * 200;
        const int hy = rem / 10, hx = (rem - hy * 10) * 2;
        pix1 = hy * HALO + hx;
        int gy = ty0 + hy - 2, gx = tx0 + hx - 2;
        const bool ok = ((unsigned)gy < HH) & ((unsigned)gx < (WW - 1));
        if (!ok) { gy = 0; gx = 0; }
        const size_t base = (size_t)b * CC * HW + (size_t)(co1 * 8) * HW
                          + (size_t)gy * WW + gx;
        #pragma unroll
        for (int j = 0; j < 8; ++j) {
            yv1[j] = *(const float2*)(y + base + (size_t)j * HW);
            xv1[j] = *(const float2*)(x + base + (size_t)j * HW);
        }
    }
    {   // pack y -> A (x loads remain in flight / in regs)
        uint4 q0, q1;
        q0.x = pkrtz(yv0[0].x, yv0[1].x); q0.y = pkrtz(yv0[2].x, yv0[3].x);
        q0.z = pkrtz(yv0[4].x, yv0[5].x); q0.w = pkrtz(yv0[6].x, yv0[7].x);
        q1.x = pkrtz(yv0[0].y, yv0[1].y); q1.y = pkrtz(yv0[2].y, yv0[3].y);
        q1.z = pkrtz(yv0[4].y, yv0[5].y); q1.w = pkrtz(yv0[6].y, yv0[7].y);
        *(uint4*)&Ah[pix0 * 32 + (co0 ^ SWZ(pix0)) * 4]           = q0;
        *(uint4*)&Ah[(pix0 + 1) * 32 + (co0 ^ SWZ(pix0 + 1)) * 4] = q1;
        if (has1) {
            q0.x = pkrtz(yv1[0].x, yv1[1].x); q0.y = pkrtz(yv1[2].x, yv1[3].x);
            q0.z = pkrtz(yv1[4].x, yv1[5].x); q0.w = pkrtz(yv1[6].x, yv1[7].x);
            q1.x = pkrtz(yv1[0].y, yv1[1].y); q1.y = pkrtz(yv1[2].y, yv1[3].y);
            q1.z = pkrtz(yv1[4].y, yv1[5].y); q1.w = pkrtz(yv1[6].y, yv1[7].y);
            *(uint4*)&Ah[pix1 * 32 + (co1 ^ SWZ(pix1)) * 4]           = q0;
            *(uint4*)&Ah[(pix1 + 1) * 32 + (co1 ^ SWZ(pix1 + 1)) * 4] = q1;
        }
    }
    __syncthreads();                                   // [1] y-halo in A

    const int wv = t >> 6;        // wave id 0..15
    const int ln = t & 63;
    const int lm = ln & 15;
    const int qd = ln >> 4;
    const int ot = wv & 3;        // this wave's 16-oc tile

    // ---- P1: q-conv from A (x-load latency hides under this); x -> B ----
    f32x4 accq[7];
    {
        const uint4 aq0 = pack_w8(wy + (ot * 16 + lm) * CC + qd * 8);
        const uint4 aq1 = pack_w8(wy + (ot * 16 + lm) * CC + qd * 8 + 32);
        #pragma unroll
        for (int k = 0; k < 7; ++k) {
            const int j = wv + k * 16;
            if (j < 100) {
                const int px = (j >> 2) * 16 + lm, sw = SWZ(px);
                const uint4 b0 = *(const uint4*)&Ah[px * 32 + ((qd    ) ^ sw) * 4];
                const uint4 b1 = *(const uint4*)&Ah[px * 32 + ((qd + 4) ^ sw) * 4];
                f32x4 a = {0.f, 0.f, 0.f, 0.f};
                a = mfma16(aq0, b0, a); a = mfma16(aq1, b1, a);
                accq[k] = a;
            }
        }
    }
    {   // pack x -> B now (loads were issued in P0)
        uint4 q0, q1;
        q0.x = pkrtz(xv0[0].x, xv0[1].x); q0.y = pkrtz(xv0[2].x, xv0[3].x);
        q0.z = pkrtz(xv0[4].x, xv0[5].x); q0.w = pkrtz(xv0[6].x, xv0[7].x);
        q1.x = pkrtz(xv0[0].y, xv0[1].y); q1.y = pkrtz(xv0[2].y, xv0[3].y);
        q1.z = pkrtz(xv0[4].y, xv0[5].y); q1.w = pkrtz(xv0[6].y, xv0[7].y);
        *(uint4*)&Bh[pix0 * 32 + (co0 ^ SWZ(pix0)) * 4]           = q0;
        *(uint4*)&Bh[(pix0 + 1) * 32 + (co0 ^ SWZ(pix0 + 1)) * 4] = q1;
        if (has1) {
            q0.x = pkrtz(xv1[0].x, xv1[1].x); q0.y = pkrtz(xv1[2].x, xv1[3].x);
            q0.z = pkrtz(xv1[4].x, xv1[5].x); q0.w = pkrtz(xv1[6].x, xv1[7].x);
            q1.x = pkrtz(xv1[0].y, xv1[1].y); q1.y = pkrtz(xv1[2].y, xv1[3].y);
            q1.z = pkrtz(xv1[4].y, xv1[5].y); q1.w = pkrtz(xv1[6].y, xv1[7].y);
            *(uint4*)&Bh[pix1 * 32 + (co1 ^ SWZ(pix1)) * 4]           = q0;
            *(uint4*)&Bh[(pix1 + 1) * 32 + (co1 ^ SWZ(pix1 + 1)) * 4] = q1;
        }
    }
    __syncthreads();                                   // [2] x in B; A reads done

    // ---- P2: q->A (write) || v-conv from B (read) || xres from B ----
    f32x4 accv[7];
    uint2 xres[4];
    {
        const float4 bq = *(const float4*)(by + ot * 16 + qd * 4);
        const int chunk = ot * 2 + (qd >> 1);
        #pragma unroll
        for (int k = 0; k < 7; ++k) {
            const int j = wv + k * 16;
            if (j < 100) {
                const int px = (j >> 2) * 16 + lm;
                const int hy = px / HALO, hx = px - hy * HALO;
                const int gy = ty0 + hy - 2, gx = tx0 + hx - 2;
                uint2 wq = {0u, 0u};
                if (((unsigned)gy < HH) & ((unsigned)gx < WW)) {
                    wq.x = pkrtz(accq[k].x + bq.x, accq[k].y + bq.y);
                    wq.y = pkrtz(accq[k].z + bq.z, accq[k].w + bq.w);
                }
                *(uint2*)&Ah[px * 32 + (chunk ^ SWZ(px)) * 4 + (qd & 1) * 2] = wq;
            }
        }
        const uint4 av0 = pack_w8(wx + (ot * 16 + lm) * CC + qd * 8);
        const uint4 av1 = pack_w8(wx + (ot * 16 + lm) * CC + qd * 8 + 32);
        #pragma unroll
        for (int k = 0; k < 7; ++k) {
            const int j = wv + k * 16;
            if (j < 100) {
                const int px = (j >> 2) * 16 + lm, sw = SWZ(px);
                const uint4 c0 = *(const uint4*)&Bh[px * 32 + ((qd    ) ^ sw) * 4];
                const uint4 c1 = *(const uint4*)&Bh[px * 32 + ((qd + 4) ^ sw) * 4];
                f32x4 v = {0.f, 0.f, 0.f, 0.f};
                v = mfma16(av0, c0, v); v = mfma16(av1, c1, v);
                accv[k] = v;
            }
        }
        #pragma unroll
        for (int k = 0; k < 4; ++k) {   // f16 x at this lane's final out px/chs
            const int px = ((wv >> 2) + k * 4) * 16 + lm;        // 0..255
            const int hpix = ((px >> 4) + 2) * HALO + (px & 15) + 2;
            xres[k] = *(const uint2*)
                &Bh[hpix * 32 + (chunk ^ SWZ(hpix)) * 4 + (qd & 1) * 2];
        }
    }
    __syncthreads();                                   // [3] q visible; B reads done

    // ---- P3: v->B (write) || scores from A (read) || softmax ----
    {
        const float4 bv = *(const float4*)(bx + ot * 16 + qd * 4);
        const int chunk = ot * 2 + (qd >> 1);
        #pragma unroll
        for (int k = 0; k < 7; ++k) {
            const int j = wv + k * 16;
            if (j < 100) {
                const int px = (j >> 2) * 16 + lm;
                const int hy = px / HALO, hx = px - hy * HALO;
                const int gy = ty0 + hy - 2, gx = tx0 + hx - 2;
                uint2 wvv = {0u, 0u};
                if (((unsigned)gy < HH) & ((unsigned)gx < WW)) {
                    wvv.x = pkrtz(accv[k].x + bv.x, accv[k].y + bv.y);
                    wvv.y = pkrtz(accv[k].z + bv.z, accv[k].w + bv.w);
                }
                *(uint2*)&Bh[px * 32 + (chunk ^ SWZ(px)) * 4 + (qd & 1) * 2] = wvv;
            }
        }
    }
    // scores: 1 pixel per thread-quad, 16 ch per sub-lane (overlaps v-writes)
    const int p    = t >> 2, sub = t & 3;              // p 0..255
    const int py   = p >> 4, pxl = p & 15;
    const int crow = (py + 2) * HALO + (pxl + 2);

    uint32 qc[8];
    {
        const int c0 = ((2 * sub)     ^ SWZ(crow)) * 4;
        const int c1 = ((2 * sub + 1) ^ SWZ(crow)) * 4;
        *(uint4*)&qc[0] = *(const uint4*)&Ah[crow * 32 + c0];
        *(uint4*)&qc[4] = *(const uint4*)&Ah[crow * 32 + c1];
    }

    float sc[25];
    #pragma unroll
    for (int dy = 0; dy < 5; ++dy)
        #pragma unroll
        for (int dx = 0; dx < 5; ++dx) {
            const int nrow = (py + dy) * HALO + (pxl + dx);
            const int c0 = ((2 * sub)     ^ SWZ(nrow)) * 4;
            const int c1 = ((2 * sub + 1) ^ SWZ(nrow)) * 4;
            const uint4 r0 = *(const uint4*)&Ah[nrow * 32 + c0];
            const uint4 r1 = *(const uint4*)&Ah[nrow * 32 + c1];
            float s = 0.f;
            s = dot2(qc[0], r0.x, s); s = dot2(qc[1], r0.y, s);
            s = dot2(qc[2], r0.z, s); s = dot2(qc[3], r0.w, s);
            s = dot2(qc[4], r1.x, s); s = dot2(qc[5], r1.y, s);
            s = dot2(qc[6], r1.z, s); s = dot2(qc[7], r1.w, s);
            s += __shfl_xor(s, 1);
            s += __shfl_xor(s, 2);      // identical across the 4 sub-lanes
            sc[dy * 5 + dx] = s;
        }

    // softmax over 25 — pairwise trees (v_max3 fusion, depth 24 -> 12)
    float mx = sc[24];
    #pragma unroll
    for (int k = 0; k < 24; k += 2) mx = fmaxf(mx, fmaxf(sc[k], sc[k + 1]));
    #pragma unroll
    for (int k = 0; k < 25; ++k) sc[k] = __expf(sc[k] - mx);
    float sum = sc[24];
    #pragma unroll
    for (int k = 0; k < 24; k += 2) sum += sc[k] + sc[k + 1];
    const float inv = 1.f / sum;

    __syncthreads();                                   // [4] v visible; A reads done

    // ---- P4: agg from B (read) || agg -> A rows 0..255 (write) ----
    h2 ag[8];
    #pragma unroll
    for (int k = 0; k < 8; ++k) ag[k] = (h2)(_Float16)0;
    #pragma unroll
    for (int dy = 0; dy < 5; ++dy)
        #pragma unroll
        for (int dx = 0; dx < 5; ++dx) {
            const int nrow = (py + dy) * HALO + (pxl + dx);
            const int c0 = ((2 * sub)     ^ SWZ(nrow)) * 4;
            const int c1 = ((2 * sub + 1) ^ SWZ(nrow)) * 4;
            const uint4 r0 = *(const uint4*)&Bh[nrow * 32 + c0];
            const uint4 r1 = *(const uint4*)&Bh[nrow * 32 + c1];
            const _Float16 af = (_Float16)(sc[dy * 5 + dx] * inv);
            const h2 a2 = {af, af};
            ag[0] += a2 * __builtin_bit_cast(h2, r0.x);
            ag[1] += a2 * __builtin_bit_cast(h2, r0.y);
            ag[2] += a2 * __builtin_bit_cast(h2, r0.z);
            ag[3] += a2 * __builtin_bit_cast(h2, r0.w);
            ag[4] += a2 * __builtin_bit_cast(h2, r1.x);
            ag[5] += a2 * __builtin_bit_cast(h2, r1.y);
            ag[6] += a2 * __builtin_bit_cast(h2, r1.z);
            ag[7] += a2 * __builtin_bit_cast(h2, r1.w);
        }
    {   // agg -> A (A is not read by anyone this phase: no barrier needed)
        const int c0 = ((2 * sub)     ^ SWZ(p)) * 4;
        const int c1 = ((2 * sub + 1) ^ SWZ(p)) * 4;
        uint4 w0, w1;
        w0.x = __builtin_bit_cast(uint32, ag[0]); w0.y = __builtin_bit_cast(uint32, ag[1]);
        w0.z = __builtin_bit_cast(uint32, ag[2]); w0.w = __builtin_bit_cast(uint32, ag[3]);
        w1.x = __builtin_bit_cast(uint32, ag[4]); w1.y = __builtin_bit_cast(uint32, ag[5]);
        w1.z = __builtin_bit_cast(uint32, ag[6]); w1.w = __builtin_bit_cast(uint32, ag[7]);
        *(uint4*)&Ah[p * 32 + c0] = w0;
        *(uint4*)&Ah[p * 32 + c1] = w1;
    }
    __syncthreads();                                   // [5]

    // ---- P5: final conv (MFMA) + bias + f16 residual from regs ----
    {
        const uint4 a0 = pack_w8(wo + (ot * 16 + lm) * CC + qd * 8);
        const uint4 a1 = pack_w8(wo + (ot * 16 + lm) * CC + qd * 8 + 32);
        const float4 bq = *(const float4*)(bo + ot * 16 + qd * 4);
        #pragma unroll
        for (int k = 0; k < 4; ++k) {
            const int px = ((wv >> 2) + k * 4) * 16 + lm, sw = SWZ(px);
            const uint4 b0 = *(const uint4*)&Ah[px * 32 + ((qd    ) ^ sw) * 4];
            const uint4 b1 = *(const uint4*)&Ah[px * 32 + ((qd + 4) ^ sw) * 4];
            f32x4 a = {0.f, 0.f, 0.f, 0.f};
            a = mfma16(a0, b0, a);
            a = mfma16(a1, b1, a);
            const int gh = ty0 + (px >> 4), gw = tx0 + (px & 15);
            const h2 xp0 = __builtin_bit_cast(h2, xres[k].x);  // ch qd*4+0,1
            const h2 xp1 = __builtin_bit_cast(h2, xres[k].y);  // ch qd*4+2,3
            const float rv[4] = {(float)xp0.x, (float)xp0.y,
                                 (float)xp1.x, (float)xp1.y};
            const float av4[4] = {a.x + bq.x, a.y + bq.y, a.z + bq.z, a.w + bq.w};
            #pragma unroll
            for (int r = 0; r < 4; ++r) {
                const int oc = ot * 16 + qd * 4 + r;
                const size_t ad = (size_t)(b * CC + oc) * HW + (size_t)gh * WW + gw;
                out[ad] = av4[r] + rv[r];   // 16 lanes -> one full 64B line
            }
        }
    }
}

// ---------------------------------------------------------------------------
extern "C" void kernel_launch(void* const* d_in, const int* in_sizes, int n_in,
                              void* d_out, int out_size, void* d_ws, size_t ws_size,
                              hipStream_t stream) {
    const float* x  = (const float*)d_in[0];
    const float* y  = (const float*)d_in[1];
    const float* wx = (const float*)d_in[2];
    const float* bx = (const float*)d_in[3];
    const float* wy = (const float*)d_in[4];
    const float* by = (const float*)d_in[5];
    const float* wo = (const float*)d_in[6];
    const float* bo = (const float*)d_in[7];
    float* out = (float*)d_out;
    (void)d_ws; (void)ws_size;

    fused_attn<<<dim3(256), 1024, 0, stream>>>(x, y, wx, bx, wy, by, wo, bo, out);
}